// Round 1
// baseline (340.854 us; speedup 1.0000x reference)
//
#include <hip/hip_runtime.h>

// Problem constants (match reference):
//   B=4, GX=480, GY=360, C_IN=64, C_OUT=32, N=480000
#define B_    4
#define GX_   480
#define GY_   360
#define GXGY  172800        // GX*GY
#define NSEG  691200        // B*GX*GY
#define CIN   64
#define COUT  32

// Order-preserving float->u32 key: f1 < f2  <=>  key(f1) < key(f2) (unsigned).
// key = bits|0x80000000 (f >= +0), ~bits (f < 0).
// key==0 corresponds to -NaN, strictly below every finite float's key, so a
// zero-filled buffer acts as the -inf init AND the "empty voxel" sentinel.
__device__ __forceinline__ unsigned f2key(float f) {
    unsigned b = __float_as_uint(f);
    return (b & 0x80000000u) ? ~b : (b | 0x80000000u);
}
__device__ __forceinline__ float key2f(unsigned k) {
    unsigned b = (k & 0x80000000u) ? (k ^ 0x80000000u) : ~k;
    return __uint_as_float(b);
}

// One thread per (point, channel). 64 consecutive threads = one wave = one
// point: pt_fea read and atomicMax destinations are both fully coalesced.
__global__ __launch_bounds__(256) void scatter_max_kernel(
    const float* __restrict__ fea,   // [N, 64]
    const int*   __restrict__ ind,   // [N, 2]
    const int*   __restrict__ bidx,  // [N]
    unsigned*    __restrict__ keys,  // [NSEG, 64]
    int N)
{
    int t = blockIdx.x * 256 + threadIdx.x;
    if (t >= N * CIN) return;
    int i = t >> 6;         // point
    int c = t & 63;         // channel
    int seg = bidx[i] * GXGY + ind[2 * i] * GY_ + ind[2 * i + 1];
    atomicMax(&keys[seg * CIN + c], f2key(fea[t]));
}

// One thread per voxel: decode 64 pooled maxima, 64x32 matvec (W in LDS,
// wave-uniform reads => broadcast), bias+ReLU, write 32 channel-strided
// floats (coalesced across consecutive-y threads). Empty voxels skip the
// 256B key read and the matvec entirely.
__global__ __launch_bounds__(256) void compress_kernel(
    const unsigned* __restrict__ keys,  // [NSEG, 64]
    const float*    __restrict__ W,     // [64, 32] row-major
    const float*    __restrict__ bias,  // [32]
    float*          __restrict__ out)   // [B, 32, GX, GY]
{
    __shared__ float sW[CIN * COUT];
    __shared__ float sb[COUT];
    for (int j = threadIdx.x; j < CIN * COUT; j += 256) sW[j] = W[j];
    if (threadIdx.x < COUT) sb[threadIdx.x] = bias[threadIdx.x];
    __syncthreads();

    int v = blockIdx.x * 256 + threadIdx.x;   // 0 .. NSEG-1 (exact grid)
    int b = v / GXGY;
    int rem = v - b * GXGY;                   // x*GY + y

    const uint4* kp = (const uint4*)(keys + (size_t)v * CIN);
    unsigned k0 = ((const unsigned*)kp)[0];

    float res[COUT];
    if (k0 != 0u) {
        float acc[COUT];
        #pragma unroll
        for (int c = 0; c < COUT; ++c) acc[c] = sb[c];
        #pragma unroll
        for (int kq = 0; kq < CIN / 4; ++kq) {
            uint4 kk = kp[kq];
            float f0 = key2f(kk.x);
            float f1 = key2f(kk.y);
            float f2 = key2f(kk.z);
            float f3 = key2f(kk.w);
            #pragma unroll
            for (int c = 0; c < COUT; ++c) {
                acc[c] += f0 * sW[(kq * 4 + 0) * COUT + c];
                acc[c] += f1 * sW[(kq * 4 + 1) * COUT + c];
                acc[c] += f2 * sW[(kq * 4 + 2) * COUT + c];
                acc[c] += f3 * sW[(kq * 4 + 3) * COUT + c];
            }
        }
        #pragma unroll
        for (int c = 0; c < COUT; ++c) res[c] = fmaxf(acc[c], 0.0f);
    } else {
        #pragma unroll
        for (int c = 0; c < COUT; ++c) res[c] = 0.0f;
    }

    float* op = out + b * (COUT * GXGY) + rem;
    #pragma unroll
    for (int c = 0; c < COUT; ++c) op[c * GXGY] = res[c];
}

extern "C" void kernel_launch(void* const* d_in, const int* in_sizes, int n_in,
                              void* d_out, int out_size, void* d_ws, size_t ws_size,
                              hipStream_t stream)
{
    const float* fea  = (const float*)d_in[0];
    const int*   ind  = (const int*)d_in[1];
    const int*   bidx = (const int*)d_in[2];
    const float* W    = (const float*)d_in[3];
    const float* bias = (const float*)d_in[4];
    float*       out  = (float*)d_out;
    unsigned*    keys = (unsigned*)d_ws;

    int N = in_sizes[0] / CIN;  // 480000

    // Zero keys: -inf init + empty sentinel in one memset (177 MB).
    hipMemsetAsync(d_ws, 0, (size_t)NSEG * CIN * sizeof(unsigned), stream);

    int tA = N * CIN;
    scatter_max_kernel<<<(tA + 255) / 256, 256, 0, stream>>>(fea, ind, bidx, keys, N);
    compress_kernel<<<NSEG / 256, 256, 0, stream>>>(keys, W, bias, out);
}

// Round 2
// 269.380 us; speedup vs baseline: 1.2653x; 1.2653x over previous
//
#include <hip/hip_runtime.h>

// Problem constants (match reference):
//   B=4, GX=480, GY=360, C_IN=64, C_OUT=32, N=480000
#define B_    4
#define GX_   480
#define GY_   360
#define GXGY  172800        // GX*GY
#define NSEG  691200        // B*GX*GY
#define CIN   64
#define COUT  32

// ---------------------------------------------------------------------------
// Pass A: build per-voxel linked lists of point indices.
//   head[seg] = last point index seen for that voxel (-1 if none)
//   next[i]   = previous head when point i was inserted
// head (2.7 MB) is L2-resident; 480K atomicExch ops, order irrelevant since
// max is commutative/associative.
// ---------------------------------------------------------------------------
__global__ __launch_bounds__(256) void build_lists_kernel(
    const int* __restrict__ ind,   // [N, 2]
    const int* __restrict__ bidx,  // [N]
    int*       __restrict__ head,  // [NSEG], pre-set to -1
    int*       __restrict__ next,  // [N]
    int N)
{
    int i = blockIdx.x * 256 + threadIdx.x;
    if (i >= N) return;
    int2 xy = ((const int2*)ind)[i];
    int seg = bidx[i] * GXGY + xy.x * GY_ + xy.y;
    next[i] = atomicExch(&head[seg], i);
}

// ---------------------------------------------------------------------------
// Pass B (fused): one thread per voxel.
//   - walk the voxel's chain, gather each point's 256B contiguous fea row
//     (float4 x16, full cacheline utilization), running max in registers
//   - 64x32 matvec with W staged in LDS (reads are wave-uniform -> broadcast,
//     consecutive c -> ds_read_b128), bias + ReLU
//   - 32 channel-strided stores, coalesced across consecutive-y threads
// Empty voxels (head == -1) skip all memory/compute and store zeros.
// ---------------------------------------------------------------------------
__global__ __launch_bounds__(256) void pool_compress_kernel(
    const float* __restrict__ fea,   // [N, 64]
    const int*   __restrict__ head,  // [NSEG]
    const int*   __restrict__ next,  // [N]
    const float* __restrict__ W,     // [64, 32] row-major
    const float* __restrict__ bias,  // [32]
    float*       __restrict__ out)   // [B, 32, GX, GY]
{
    __shared__ float sW[CIN * COUT];
    __shared__ float sb[COUT];
    for (int j = threadIdx.x; j < CIN * COUT; j += 256) sW[j] = W[j];
    if (threadIdx.x < COUT) sb[threadIdx.x] = bias[threadIdx.x];
    __syncthreads();

    int v = blockIdx.x * 256 + threadIdx.x;   // 0 .. NSEG-1 (exact grid)
    int b = v / GXGY;
    int rem = v - b * GXGY;                   // x*GY + y

    int i = head[v];
    float res[COUT];

    if (i >= 0) {
        // First point: direct load of its 64-float row.
        float4 mx[CIN / 4];
        {
            const float4* fp = (const float4*)(fea + (size_t)i * CIN);
            #pragma unroll
            for (int q = 0; q < CIN / 4; ++q) mx[q] = fp[q];
            i = next[i];
        }
        // Remaining points (avg chain length ~1.4 for occupied voxels).
        while (i >= 0) {
            const float4* fp = (const float4*)(fea + (size_t)i * CIN);
            #pragma unroll
            for (int q = 0; q < CIN / 4; ++q) {
                float4 t = fp[q];
                mx[q].x = fmaxf(mx[q].x, t.x);
                mx[q].y = fmaxf(mx[q].y, t.y);
                mx[q].z = fmaxf(mx[q].z, t.z);
                mx[q].w = fmaxf(mx[q].w, t.w);
            }
            i = next[i];
        }

        // 64x32 matvec: acc[c] = bias[c] + sum_k mx[k] * W[k][c]
        float acc[COUT];
        #pragma unroll
        for (int c = 0; c < COUT; ++c) acc[c] = sb[c];
        #pragma unroll
        for (int q = 0; q < CIN / 4; ++q) {
            float f0 = mx[q].x, f1 = mx[q].y, f2 = mx[q].z, f3 = mx[q].w;
            const float* w0 = &sW[(q * 4 + 0) * COUT];
            const float* w1 = &sW[(q * 4 + 1) * COUT];
            const float* w2 = &sW[(q * 4 + 2) * COUT];
            const float* w3 = &sW[(q * 4 + 3) * COUT];
            #pragma unroll
            for (int c = 0; c < COUT; ++c) {
                acc[c] = fmaf(f0, w0[c], acc[c]);
                acc[c] = fmaf(f1, w1[c], acc[c]);
                acc[c] = fmaf(f2, w2[c], acc[c]);
                acc[c] = fmaf(f3, w3[c], acc[c]);
            }
        }
        #pragma unroll
        for (int c = 0; c < COUT; ++c) res[c] = fmaxf(acc[c], 0.0f);
    } else {
        #pragma unroll
        for (int c = 0; c < COUT; ++c) res[c] = 0.0f;
    }

    float* op = out + b * (COUT * GXGY) + rem;
    #pragma unroll
    for (int c = 0; c < COUT; ++c) op[c * GXGY] = res[c];
}

extern "C" void kernel_launch(void* const* d_in, const int* in_sizes, int n_in,
                              void* d_out, int out_size, void* d_ws, size_t ws_size,
                              hipStream_t stream)
{
    const float* fea  = (const float*)d_in[0];
    const int*   ind  = (const int*)d_in[1];
    const int*   bidx = (const int*)d_in[2];
    const float* W    = (const float*)d_in[3];
    const float* bias = (const float*)d_in[4];
    float*       out  = (float*)d_out;

    int N = in_sizes[0] / CIN;  // 480000

    int* head = (int*)d_ws;                    // NSEG ints (2.76 MB)
    int* next = (int*)d_ws + NSEG;             // N ints (1.92 MB)

    // head = -1 everywhere (0xFFFFFFFF). Only 2.76 MB (was 177 MB).
    hipMemsetAsync(head, 0xFF, (size_t)NSEG * sizeof(int), stream);

    build_lists_kernel<<<(N + 255) / 256, 256, 0, stream>>>(ind, bidx, head, next, N);
    pool_compress_kernel<<<NSEG / 256, 256, 0, stream>>>(fea, head, next, W, bias, out);
}